// Round 13
// baseline (88.688 us; speedup 1.0000x reference)
//
#include <hip/hip_runtime.h>

typedef unsigned short u16;
typedef unsigned int u32;
typedef __attribute__((ext_vector_type(8))) short short8;
typedef __attribute__((ext_vector_type(4))) float f32x4;

__device__ __forceinline__ u16 f2bf(float f) {
    unsigned u = __float_as_uint(f);
    return (u16)((u + 0x7FFFu + ((u >> 16) & 1u)) >> 16);  // RNE
}
__device__ __forceinline__ u32 pack2(float a, float b) {
    return ((u32)f2bf(b) << 16) | (u32)f2bf(a);
}
__device__ __forceinline__ float bfhi(u32 w) { return __uint_as_float(w & 0xFFFF0000u); }
__device__ __forceinline__ float bflo(u32 w) { return __uint_as_float(w << 16); }

// ---- DPP row-rotate helpers (16-lane rows) ----
#define ROR1 0x121
#define ROR2 0x122
#define ROR4 0x124
#define ROR8 0x128
template<int C> __device__ __forceinline__ float dppf(float x) {
    int i = __float_as_int(x);
    return __int_as_float(__builtin_amdgcn_update_dpp(i, i, C, 0xF, 0xF, false));
}
template<int C> __device__ __forceinline__ int dppi(int x) {
    return __builtin_amdgcn_update_dpp(x, x, C, 0xF, 0xF, false);
}

// ---------------------------------------------------------------------------
// R11-proven unified GEMM (depth-2 — DO NOT deepen; depth-4 regressed R12):
// C[64][c0..c0+128) over k-slice [k0,k0+kchunk).  grid (N/128, KS), 256 thr,
// __launch_bounds__(256,2).  W read: threads 0..15 cover one full 512B row
// segment (coalesced); W LDS k-pair-major [kp][132] u32.
// SRC 0: A global bf16 [64][4096].  SRC 1: build X from emb (reshape quirk
//        X[r][e] = emb[2*(r&3)+(e>=128)][r>>2][e&127]).
// EPI 0: bf16 partial -> Cp16[slice].  EPI 1: bias+leaky -> bf16 Ho.
// nit = kchunk/32 must be EVEN.
// ---------------------------------------------------------------------------
template<int SRC, int EPI>
__global__ __launch_bounds__(256, 2) void k_gemm(
    const u16* __restrict__ A, const float* __restrict__ emb,
    const float* __restrict__ W, const float* __restrict__ bias,
    u16* __restrict__ Cp16, u16* __restrict__ Ho,
    int N, int kchunk)
{
    __shared__ __align__(16) u16 Alds[64][40];     // 5120 B
    __shared__ __align__(16) u32 Wlds[16 * 132];   // 8448 B
    int tid = threadIdx.x;
    int wv = tid >> 6, lane = tid & 63, c = lane & 15, g = lane >> 4;
    int c0 = blockIdx.x * 128;
    int k0 = blockIdx.y * kchunk;
    int nit = kchunk >> 5;

    int ar = tid >> 2, aseg = tid & 3;          // A staging: row, 8-elem seg
    int kp = tid >> 4, cbase = (tid & 15) * 8;  // W staging: k-pair, col base

    f32x4 acc[8];
    #pragma unroll
    for (int n = 0; n < 8; ++n) acc[n] = (f32x4){0.f, 0.f, 0.f, 0.f};

    auto loadA = [&](int kc, uint4& av) {
        if (SRC == 0) {
            av = *(const uint4*)(A + (size_t)ar * 4096 + k0 + kc + aseg * 8);
        } else {
            int e0 = kc + aseg * 8;
            int b = 2 * (ar & 3) + (e0 >> 7), d = e0 & 127;
            const float4* s = (const float4*)(emb + (b * 16 + (ar >> 2)) * 128 + d);
            float4 f0 = s[0], f1 = s[1];
            av.x = pack2(f0.x, f0.y); av.y = pack2(f0.z, f0.w);
            av.z = pack2(f1.x, f1.y); av.w = pack2(f1.z, f1.w);
        }
    };
    auto loadW = [&](int kc, float4& q0, float4& q1, float4& q2, float4& q3) {
        const float* s0 = W + (size_t)(k0 + kc + 2 * kp) * N + c0 + cbase;
        q0 = ((const float4*)s0)[0]; q1 = ((const float4*)s0)[1];
        const float* s1 = s0 + N;
        q2 = ((const float4*)s1)[0]; q3 = ((const float4*)s1)[1];
    };
    auto stage = [&](const uint4& av, const float4& q0, const float4& q1,
                     const float4& q2, const float4& q3) {
        *(uint4*)&Alds[ar][aseg * 8] = av;
        uint4 w0, w1;
        w0.x = pack2(q0.x, q2.x); w0.y = pack2(q0.y, q2.y);
        w0.z = pack2(q0.z, q2.z); w0.w = pack2(q0.w, q2.w);
        w1.x = pack2(q1.x, q3.x); w1.y = pack2(q1.y, q3.y);
        w1.z = pack2(q1.z, q3.z); w1.w = pack2(q1.w, q3.w);
        uint4* wd = (uint4*)&Wlds[kp * 132 + cbase];
        wd[0] = w0; wd[1] = w1;
    };
    auto compute = [&]() {
        short8 a8 = *(const short8*)&Alds[wv * 16 + c][g * 8];
        #pragma unroll
        for (int n = 0; n < 8; ++n) {
            int base = n * 16 + c;
            union { u32 u[4]; short8 s; } bb;
            bb.u[0] = Wlds[(g * 4 + 0) * 132 + base];
            bb.u[1] = Wlds[(g * 4 + 1) * 132 + base];
            bb.u[2] = Wlds[(g * 4 + 2) * 132 + base];
            bb.u[3] = Wlds[(g * 4 + 3) * 132 + base];
            acc[n] = __builtin_amdgcn_mfma_f32_16x16x32_bf16(a8, bb.s, acc[n], 0, 0, 0);
        }
    };

    // ---- depth-2 pipeline, two named register sets (static indexing)
    uint4 avA, avB;
    float4 qA0, qA1, qA2, qA3, qB0, qB1, qB2, qB3;
    loadA(0, avA);  loadW(0, qA0, qA1, qA2, qA3);
    loadA(32, avB); loadW(32, qB0, qB1, qB2, qB3);

    for (int it = 0; it < nit; it += 2) {
        stage(avA, qA0, qA1, qA2, qA3);
        __syncthreads();
        if (it + 2 < nit) { loadA((it + 2) * 32, avA); loadW((it + 2) * 32, qA0, qA1, qA2, qA3); }
        compute();
        __syncthreads();

        stage(avB, qB0, qB1, qB2, qB3);
        __syncthreads();
        if (it + 3 < nit) { loadA((it + 3) * 32, avB); loadW((it + 3) * 32, qB0, qB1, qB2, qB3); }
        compute();
        __syncthreads();
    }

    // ---- epilogue (D layout: col = lane&15, row = g*4+rr)
    #pragma unroll
    for (int n = 0; n < 8; ++n) {
        #pragma unroll
        for (int rr = 0; rr < 4; ++rr) {
            int grow = wv * 16 + g * 4 + rr;
            int gcol = c0 + n * 16 + c;
            float v = acc[n][rr];
            if (EPI == 0) {
                Cp16[(size_t)blockIdx.y * 64 * N + (size_t)grow * N + gcol] = f2bf(v);
            } else {
                v += bias[gcol];
                v = (v >= 0.f) ? v : 0.01f * v;
                Ho[(size_t)grow * N + gcol] = f2bf(v);
            }
        }
    }
}

// ---------------------------------------------------------------------------
// Vectorized reduce of bf16 split-K partials + bias + leaky -> bf16 H.
// Each thread: 8 consecutive elems via uint4 per slice.  grid = 64*N/2048.
// ---------------------------------------------------------------------------
__global__ __launch_bounds__(256) void k_reduce(
    const u16* __restrict__ Cp16, const float* __restrict__ bias,
    u16* __restrict__ Hb, int N, int ksplit)
{
    int e0 = (blockIdx.x * 256 + threadIdx.x) * 8;
    float s[8];
    #pragma unroll
    for (int j = 0; j < 8; ++j) s[j] = 0.f;
    for (int k = 0; k < ksplit; ++k) {
        uint4 w = *(const uint4*)(Cp16 + (size_t)k * 64 * N + e0);
        s[0] += bflo(w.x); s[1] += bfhi(w.x);
        s[2] += bflo(w.y); s[3] += bfhi(w.y);
        s[4] += bflo(w.z); s[5] += bfhi(w.z);
        s[6] += bflo(w.w); s[7] += bfhi(w.w);
    }
    int colb = e0 & (N - 1);
    u16 o[8];
    #pragma unroll
    for (int j = 0; j < 8; ++j) {
        float a = s[j] + bias[colb + j];
        a = (a >= 0.f) ? a : 0.01f * a;
        o[j] = f2bf(a);
    }
    *(uint4*)(Hb + e0) = *(uint4*)o;
}

// ---------------------------------------------------------------------------
// Fused: L4 partial-reduce + bias + leaky + sigmoid -> LDS pol, then 50
// power iterations (VALU/DPP) + factored output reduction.  1024 threads.
// Cp16: [32][16384] bf16 L4 partials (1 MB).  pol never touches global.
// ---------------------------------------------------------------------------
__global__ __launch_bounds__(1024) void k_power_out(
    const u16* __restrict__ Cp16,   // [32][16384] bf16 L4 partials
    const float* __restrict__ bias, // [256] b4
    const float* __restrict__ Ts,   // [8][16][16]
    float* __restrict__ out)        // [8][16]
{
    __shared__ float pol_lds[16384];
    __shared__ float w_lds[64][16];
    __shared__ float Ts_lds[2048];
    __shared__ float Cmat[8][16];

    int tid = threadIdx.x;
    int m = tid >> 4, r = tid & 15;

    {   // reduce 32 slices for this thread's 16 elems; bias+leaky+sigmoid
        int e0 = tid * 16;
        float s[16];
        #pragma unroll
        for (int j = 0; j < 16; ++j) s[j] = 0.f;
        for (int k = 0; k < 32; ++k) {
            const uint4* q = (const uint4*)(Cp16 + (size_t)k * 16384 + e0);
            uint4 w0 = q[0], w1 = q[1];
            s[0]  += bflo(w0.x); s[1]  += bfhi(w0.x);
            s[2]  += bflo(w0.y); s[3]  += bfhi(w0.y);
            s[4]  += bflo(w0.z); s[5]  += bfhi(w0.z);
            s[6]  += bflo(w0.w); s[7]  += bfhi(w0.w);
            s[8]  += bflo(w1.x); s[9]  += bfhi(w1.x);
            s[10] += bflo(w1.y); s[11] += bfhi(w1.y);
            s[12] += bflo(w1.z); s[13] += bfhi(w1.z);
            s[14] += bflo(w1.w); s[15] += bfhi(w1.w);
        }
        int colb = e0 & 255;
        #pragma unroll
        for (int j = 0; j < 16; ++j) {
            float a = s[j] + bias[colb + j];
            a = (a >= 0.f) ? a : 0.01f * a;
            pol_lds[e0 + j] = 1.0f / (1.0f + __expf(-a));
        }
    }
    Ts_lds[tid] = Ts[tid];
    Ts_lds[tid + 1024] = Ts[tid + 1024];
    __syncthreads();

    // gather row r of matrix m with DPP-rotated index (matches va rotation)
    float Mr[8], Ms[8];
    {
        int mb = m * 256 + r * 16;
        int idx = r;
        #pragma unroll
        for (int k = 0; k < 8; ++k) { Mr[k] = pol_lds[mb + idx]; idx = dppi<ROR1>(idx); }
        #pragma unroll
        for (int k = 0; k < 8; ++k) { Ms[k] = pol_lds[mb + idx]; idx = dppi<ROR1>(idx); }
    }

    float v = 1.0f;
    #pragma unroll 1
    for (int it = 0; it < 50; ++it) {
        float va = v, vb = dppf<ROR8>(v);
        float w = 0.f, w2 = 0.f;
        #pragma unroll
        for (int k = 0; k < 8; ++k) {
            w  = fmaf(Mr[k], va, w);
            w2 = fmaf(Ms[k], vb, w2);
            if (k < 7) { va = dppf<ROR1>(va); vb = dppf<ROR1>(vb); }
        }
        w += w2;
        if ((it & 7) == 7) {   // positive-sum renorm; scale cancels in output
            float s = w;
            s += dppf<ROR8>(s); s += dppf<ROR4>(s);
            s += dppf<ROR2>(s); s += dppf<ROR1>(s);
            w *= 1.0f / s;
        }
        v = w;
    }
    w_lds[m][r] = v;
    __syncthreads();

    if (tid < 128) {
        int b = tid >> 4, x = tid & 15;
        float s = 0.f;
        if (b < 4) {                             // R[b][s=x] = sum_t Ts[b][x][t]
            const float* row = &Ts_lds[(b * 16 + x) * 16];
            #pragma unroll
            for (int t = 0; t < 16; ++t) s += row[t];
        } else {                                 // C[b][t=x]
            int j = b - 4;
            #pragma unroll
            for (int si = 0; si < 16; ++si)
                s += Ts_lds[(b * 16 + si) * 16 + x] / w_lds[x * 4 + j][si];
        }
        Cmat[b][x] = s;
    }
    __syncthreads();

    if (tid < 128) {
        int b = tid >> 4, n = tid & 15;
        float o = 0.f;
        if (b < 4) {
            #pragma unroll
            for (int si = 0; si < 16; ++si) {
                const float* wr = w_lds[si * 4 + b];
                o += wr[n] / wr[si] * Cmat[b][si];
            }
        } else {
            int j = b - 4;
            #pragma unroll
            for (int t = 0; t < 16; ++t)
                o += w_lds[t * 4 + j][n] * Cmat[b][t];
        }
        out[b * 16 + n] = o;
    }
}

// ---------------------------------------------------------------------------
extern "C" void kernel_launch(void* const* d_in, const int* in_sizes, int n_in,
                              void* d_out, int out_size, void* d_ws, size_t ws_size,
                              hipStream_t stream)
{
    const float* emb = (const float*)d_in[0];
    const float* Ts  = (const float*)d_in[2];
    const float* W1  = (const float*)d_in[3];  const float* b1 = (const float*)d_in[4];
    const float* W2  = (const float*)d_in[5];  const float* b2 = (const float*)d_in[6];
    const float* W3  = (const float*)d_in[7];  const float* b3 = (const float*)d_in[8];
    const float* W4  = (const float*)d_in[9];  const float* b4 = (const float*)d_in[10];
    float* outp = (float*)d_out;

    char* ws = (char*)d_ws;
    u16*   Ha  = (u16*)(ws + 0);            // 512 KB  [64][4096] bf16
    u16*   Hb  = (u16*)(ws + 524288);       // 512 KB  [64][4096] bf16
    u16*   Cp  = (u16*)(ws + 1048576);      //  bf16 split-K partials (KS*512 KB)

    // adaptive mid-layer ksplit: 16 if workspace permits (bf16: KS*512 KB)
    size_t need16 = (size_t)1048576 + (size_t)16 * 524288;   // ~9.4 MB
    int KS = (ws_size >= need16) ? 16 : 8;
    int kchunk = 4096 / KS;   // nit = 8 or 16, both even

    // L1: fused build-X + GEMM + epilogue -> Ha   (K=256, nit=8)
    k_gemm<1, 1><<<dim3(32, 1), 256, 0, stream>>>(
        nullptr, emb, W1, b1, nullptr, Ha, 4096, 256);

    // L2: split-K -> Cp (bf16); reduce -> Hb
    k_gemm<0, 0><<<dim3(32, KS), 256, 0, stream>>>(
        Ha, nullptr, W2, nullptr, Cp, nullptr, 4096, kchunk);
    k_reduce<<<128, 256, 0, stream>>>(Cp, b2, Hb, 4096, KS);

    // L3: split-K -> Cp; reduce -> Ha
    k_gemm<0, 0><<<dim3(32, KS), 256, 0, stream>>>(
        Hb, nullptr, W3, nullptr, Cp, nullptr, 4096, kchunk);
    k_reduce<<<128, 256, 0, stream>>>(Cp, b3, Ha, 4096, KS);

    // L4: N=256, split-K KS=32 (kchunk=128, nit=4) -> Cp (1 MB bf16)
    k_gemm<0, 0><<<dim3(2, 32), 256, 0, stream>>>(
        Ha, nullptr, W4, nullptr, Cp, nullptr, 256, 128);

    // Fused L4-reduce + sigmoid + power iteration + factored output
    k_power_out<<<1, 1024, 0, stream>>>(Cp, b4, Ts, outp);

    (void)in_sizes; (void)n_in; (void)out_size; (void)ws_size;
}

// Round 14
// 80.829 us; speedup vs baseline: 1.0972x; 1.0972x over previous
//
#include <hip/hip_runtime.h>

typedef unsigned short u16;
typedef unsigned int u32;
typedef __attribute__((ext_vector_type(8))) short short8;
typedef __attribute__((ext_vector_type(4))) float f32x4;

__device__ __forceinline__ u16 f2bf(float f) {
    unsigned u = __float_as_uint(f);
    return (u16)((u + 0x7FFFu + ((u >> 16) & 1u)) >> 16);  // RNE
}
__device__ __forceinline__ u32 pack2(float a, float b) {
    return ((u32)f2bf(b) << 16) | (u32)f2bf(a);
}
__device__ __forceinline__ float bf2f(u16 w) { return __uint_as_float((u32)w << 16); }

// ---- DPP row-rotate helpers (16-lane rows) ----
#define ROR1 0x121
#define ROR2 0x122
#define ROR4 0x124
#define ROR8 0x128
template<int C> __device__ __forceinline__ float dppf(float x) {
    int i = __float_as_int(x);
    return __int_as_float(__builtin_amdgcn_update_dpp(i, i, C, 0xF, 0xF, false));
}
template<int C> __device__ __forceinline__ int dppi(int x) {
    return __builtin_amdgcn_update_dpp(x, x, C, 0xF, 0xF, false);
}

// ---------------------------------------------------------------------------
// R11-proven unified GEMM (depth-2 — depth-4 regressed R12; DO NOT touch):
// C[64][c0..c0+128) over k-slice [k0,k0+kchunk).  grid (N/128, KS), 256 thr,
// __launch_bounds__(256,2).  W read: threads 0..15 cover one full 512B row
// segment (coalesced); W LDS k-pair-major [kp][132] u32.
// SRC 0: A global bf16 [64][4096].  SRC 1: build X from emb (reshape quirk
//        X[r][e] = emb[2*(r&3)+(e>=128)][r>>2][e&127]).
// EPI 0: bf16 partial -> Cp16[slice].  EPI 1: bias+leaky -> bf16 Ho.
// nit = kchunk/32 must be EVEN.
// ---------------------------------------------------------------------------
template<int SRC, int EPI>
__global__ __launch_bounds__(256, 2) void k_gemm(
    const u16* __restrict__ A, const float* __restrict__ emb,
    const float* __restrict__ W, const float* __restrict__ bias,
    u16* __restrict__ Cp16, u16* __restrict__ Ho,
    int N, int kchunk)
{
    __shared__ __align__(16) u16 Alds[64][40];     // 5120 B
    __shared__ __align__(16) u32 Wlds[16 * 132];   // 8448 B
    int tid = threadIdx.x;
    int wv = tid >> 6, lane = tid & 63, c = lane & 15, g = lane >> 4;
    int c0 = blockIdx.x * 128;
    int k0 = blockIdx.y * kchunk;
    int nit = kchunk >> 5;

    int ar = tid >> 2, aseg = tid & 3;          // A staging: row, 8-elem seg
    int kp = tid >> 4, cbase = (tid & 15) * 8;  // W staging: k-pair, col base

    f32x4 acc[8];
    #pragma unroll
    for (int n = 0; n < 8; ++n) acc[n] = (f32x4){0.f, 0.f, 0.f, 0.f};

    auto loadA = [&](int kc, uint4& av) {
        if (SRC == 0) {
            av = *(const uint4*)(A + (size_t)ar * 4096 + k0 + kc + aseg * 8);
        } else {
            int e0 = kc + aseg * 8;
            int b = 2 * (ar & 3) + (e0 >> 7), d = e0 & 127;
            const float4* s = (const float4*)(emb + (b * 16 + (ar >> 2)) * 128 + d);
            float4 f0 = s[0], f1 = s[1];
            av.x = pack2(f0.x, f0.y); av.y = pack2(f0.z, f0.w);
            av.z = pack2(f1.x, f1.y); av.w = pack2(f1.z, f1.w);
        }
    };
    auto loadW = [&](int kc, float4& q0, float4& q1, float4& q2, float4& q3) {
        const float* s0 = W + (size_t)(k0 + kc + 2 * kp) * N + c0 + cbase;
        q0 = ((const float4*)s0)[0]; q1 = ((const float4*)s0)[1];
        const float* s1 = s0 + N;
        q2 = ((const float4*)s1)[0]; q3 = ((const float4*)s1)[1];
    };
    auto stage = [&](const uint4& av, const float4& q0, const float4& q1,
                     const float4& q2, const float4& q3) {
        *(uint4*)&Alds[ar][aseg * 8] = av;
        uint4 w0, w1;
        w0.x = pack2(q0.x, q2.x); w0.y = pack2(q0.y, q2.y);
        w0.z = pack2(q0.z, q2.z); w0.w = pack2(q0.w, q2.w);
        w1.x = pack2(q1.x, q3.x); w1.y = pack2(q1.y, q3.y);
        w1.z = pack2(q1.z, q3.z); w1.w = pack2(q1.w, q3.w);
        uint4* wd = (uint4*)&Wlds[kp * 132 + cbase];
        wd[0] = w0; wd[1] = w1;
    };
    auto compute = [&]() {
        short8 a8 = *(const short8*)&Alds[wv * 16 + c][g * 8];
        #pragma unroll
        for (int n = 0; n < 8; ++n) {
            int base = n * 16 + c;
            union { u32 u[4]; short8 s; } bb;
            bb.u[0] = Wlds[(g * 4 + 0) * 132 + base];
            bb.u[1] = Wlds[(g * 4 + 1) * 132 + base];
            bb.u[2] = Wlds[(g * 4 + 2) * 132 + base];
            bb.u[3] = Wlds[(g * 4 + 3) * 132 + base];
            acc[n] = __builtin_amdgcn_mfma_f32_16x16x32_bf16(a8, bb.s, acc[n], 0, 0, 0);
        }
    };

    // ---- depth-2 pipeline, two named register sets (static indexing)
    uint4 avA, avB;
    float4 qA0, qA1, qA2, qA3, qB0, qB1, qB2, qB3;
    loadA(0, avA);  loadW(0, qA0, qA1, qA2, qA3);
    loadA(32, avB); loadW(32, qB0, qB1, qB2, qB3);

    for (int it = 0; it < nit; it += 2) {
        stage(avA, qA0, qA1, qA2, qA3);
        __syncthreads();
        if (it + 2 < nit) { loadA((it + 2) * 32, avA); loadW((it + 2) * 32, qA0, qA1, qA2, qA3); }
        compute();
        __syncthreads();

        stage(avB, qB0, qB1, qB2, qB3);
        __syncthreads();
        if (it + 3 < nit) { loadA((it + 3) * 32, avB); loadW((it + 3) * 32, qB0, qB1, qB2, qB3); }
        compute();
        __syncthreads();
    }

    // ---- epilogue (D layout: col = lane&15, row = g*4+rr)
    #pragma unroll
    for (int n = 0; n < 8; ++n) {
        #pragma unroll
        for (int rr = 0; rr < 4; ++rr) {
            int grow = wv * 16 + g * 4 + rr;
            int gcol = c0 + n * 16 + c;
            float v = acc[n][rr];
            if (EPI == 0) {
                Cp16[(size_t)blockIdx.y * 64 * N + (size_t)grow * N + gcol] = f2bf(v);
            } else {
                v += bias[gcol];
                v = (v >= 0.f) ? v : 0.01f * v;
                Ho[(size_t)grow * N + gcol] = f2bf(v);
            }
        }
    }
}

// ---------------------------------------------------------------------------
// Reduce bf16 split-K partials + bias + leaky; mode 0 -> bf16 H, mode 1 ->
// sigmoid(leaky) fp32.  grid = 64*N/256.  (R11-proven scalar form.)
// ---------------------------------------------------------------------------
__global__ void k_reduce(const u16* __restrict__ Cp16, const float* __restrict__ bias,
                         u16* __restrict__ Hb, float* __restrict__ Pf,
                         int N, int ksplit, int mode)
{
    int idx = blockIdx.x * 256 + threadIdx.x;
    int col = idx & (N - 1);
    float s = bias[col];
    #pragma unroll 4
    for (int k = 0; k < ksplit; ++k) s += bf2f(Cp16[(size_t)k * 64 * N + idx]);
    float a = (s >= 0.f) ? s : 0.01f * s;
    if (mode == 0) Hb[idx] = f2bf(a);
    else           Pf[idx] = 1.0f / (1.0f + __expf(-a));
}

// ---------------------------------------------------------------------------
// 50 power iterations (VALU/DPP only) + factored output reduction.  Proven.
// ---------------------------------------------------------------------------
__global__ __launch_bounds__(1024) void k_power_out(
    const float* __restrict__ pol,  // [64][16][16] fp32 (post-sigmoid)
    const float* __restrict__ Ts,   // [8][16][16]
    float* __restrict__ out)        // [8][16]
{
    __shared__ float pol_lds[16384];
    __shared__ float w_lds[64][16];
    __shared__ float Ts_lds[2048];
    __shared__ float Cmat[8][16];

    int tid = threadIdx.x;
    int m = tid >> 4, r = tid & 15;

    {   // stage all 64 matrices (64 KB) to LDS
        const float4* p4 = (const float4*)(pol + tid * 16);
        float4* q4 = (float4*)&pol_lds[tid * 16];
        q4[0] = p4[0]; q4[1] = p4[1]; q4[2] = p4[2]; q4[3] = p4[3];
    }
    Ts_lds[tid] = Ts[tid];
    Ts_lds[tid + 1024] = Ts[tid + 1024];
    __syncthreads();

    // gather row r of matrix m with DPP-rotated index (matches va rotation)
    float Mr[8], Ms[8];
    {
        int mb = m * 256 + r * 16;
        int idx = r;
        #pragma unroll
        for (int k = 0; k < 8; ++k) { Mr[k] = pol_lds[mb + idx]; idx = dppi<ROR1>(idx); }
        #pragma unroll
        for (int k = 0; k < 8; ++k) { Ms[k] = pol_lds[mb + idx]; idx = dppi<ROR1>(idx); }
    }

    float v = 1.0f;
    #pragma unroll 1
    for (int it = 0; it < 50; ++it) {
        float va = v, vb = dppf<ROR8>(v);
        float w = 0.f, w2 = 0.f;
        #pragma unroll
        for (int k = 0; k < 8; ++k) {
            w  = fmaf(Mr[k], va, w);
            w2 = fmaf(Ms[k], vb, w2);
            if (k < 7) { va = dppf<ROR1>(va); vb = dppf<ROR1>(vb); }
        }
        w += w2;
        if ((it & 7) == 7) {   // positive-sum renorm; scale cancels in output
            float s = w;
            s += dppf<ROR8>(s); s += dppf<ROR4>(s);
            s += dppf<ROR2>(s); s += dppf<ROR1>(s);
            w *= 1.0f / s;
        }
        v = w;
    }
    w_lds[m][r] = v;
    __syncthreads();

    if (tid < 128) {
        int b = tid >> 4, x = tid & 15;
        float s = 0.f;
        if (b < 4) {                             // R[b][s=x] = sum_t Ts[b][x][t]
            const float* row = &Ts_lds[(b * 16 + x) * 16];
            #pragma unroll
            for (int t = 0; t < 16; ++t) s += row[t];
        } else {                                 // C[b][t=x]
            int j = b - 4;
            #pragma unroll
            for (int si = 0; si < 16; ++si)
                s += Ts_lds[(b * 16 + si) * 16 + x] / w_lds[x * 4 + j][si];
        }
        Cmat[b][x] = s;
    }
    __syncthreads();

    if (tid < 128) {
        int b = tid >> 4, n = tid & 15;
        float o = 0.f;
        if (b < 4) {
            #pragma unroll
            for (int si = 0; si < 16; ++si) {
                const float* wr = w_lds[si * 4 + b];
                o += wr[n] / wr[si] * Cmat[b][si];
            }
        } else {
            int j = b - 4;
            #pragma unroll
            for (int t = 0; t < 16; ++t)
                o += w_lds[t * 4 + j][n] * Cmat[b][t];
        }
        out[b * 16 + n] = o;
    }
}

// ---------------------------------------------------------------------------
extern "C" void kernel_launch(void* const* d_in, const int* in_sizes, int n_in,
                              void* d_out, int out_size, void* d_ws, size_t ws_size,
                              hipStream_t stream)
{
    const float* emb = (const float*)d_in[0];
    const float* Ts  = (const float*)d_in[2];
    const float* W1  = (const float*)d_in[3];  const float* b1 = (const float*)d_in[4];
    const float* W2  = (const float*)d_in[5];  const float* b2 = (const float*)d_in[6];
    const float* W3  = (const float*)d_in[7];  const float* b3 = (const float*)d_in[8];
    const float* W4  = (const float*)d_in[9];  const float* b4 = (const float*)d_in[10];
    float* outp = (float*)d_out;

    char* ws = (char*)d_ws;
    u16*   Ha  = (u16*)(ws + 0);            // 512 KB  [64][4096] bf16
    u16*   Hb  = (u16*)(ws + 524288);       // 512 KB  [64][4096] bf16
    float* pol = (float*)(ws + 1048576);    //  64 KB  [64][16][16] fp32
    u16*   Cp  = (u16*)(ws + 1114112);      //  bf16 split-K partials (KS*512 KB)

    // mid-layer ksplit: 32 -> grid 1024 = 4 blocks/CU (16 waves/CU) for
    // latency hiding; fall back 16 (== proven R11) then 8 by workspace.
    size_t base = 1114112;
    int KS;
    if      (ws_size >= base + (size_t)32 * 524288) KS = 32;   // ~17.9 MB
    else if (ws_size >= base + (size_t)16 * 524288) KS = 16;   // ~9.5 MB
    else                                            KS = 8;
    int kchunk = 4096 / KS;   // 128/256/512 -> nit = 4/8/16, all even

    // L1: fused build-X + GEMM + epilogue -> Ha   (K=256, nit=8)
    k_gemm<1, 1><<<dim3(32, 1), 256, 0, stream>>>(
        nullptr, emb, W1, b1, nullptr, Ha, 4096, 256);

    // L2: split-K -> Cp (bf16); reduce -> Hb
    k_gemm<0, 0><<<dim3(32, KS), 256, 0, stream>>>(
        Ha, nullptr, W2, nullptr, Cp, nullptr, 4096, kchunk);
    k_reduce<<<1024, 256, 0, stream>>>(Cp, b2, Hb, nullptr, 4096, KS, 0);

    // L3: split-K -> Cp; reduce -> Ha
    k_gemm<0, 0><<<dim3(32, KS), 256, 0, stream>>>(
        Hb, nullptr, W3, nullptr, Cp, nullptr, 4096, kchunk);
    k_reduce<<<1024, 256, 0, stream>>>(Cp, b3, Ha, nullptr, 4096, KS, 0);

    // L4: N=256, split-K KS=32 (kchunk=128, nit=4) -> Cp; reduce+sigmoid -> pol
    k_gemm<0, 0><<<dim3(2, 32), 256, 0, stream>>>(
        Ha, nullptr, W4, nullptr, Cp, nullptr, 256, 128);
    k_reduce<<<64, 256, 0, stream>>>(Cp, b4, nullptr, pol, 256, 32, 1);

    // Power iteration + factored output
    k_power_out<<<1, 1024, 0, stream>>>(pol, Ts, outp);

    (void)in_sizes; (void)n_in; (void)out_size; (void)ws_size;
}

// Round 15
// 75.807 us; speedup vs baseline: 1.1699x; 1.0662x over previous
//
#include <hip/hip_runtime.h>

typedef unsigned short u16;
typedef unsigned int u32;
typedef __attribute__((ext_vector_type(8))) short short8;
typedef __attribute__((ext_vector_type(4))) float f32x4;

__device__ __forceinline__ u16 f2bf(float f) {
    unsigned u = __float_as_uint(f);
    return (u16)((u + 0x7FFFu + ((u >> 16) & 1u)) >> 16);  // RNE
}
__device__ __forceinline__ u32 pack2(float a, float b) {
    return ((u32)f2bf(b) << 16) | (u32)f2bf(a);
}
__device__ __forceinline__ float bf2f(u16 w) { return __uint_as_float((u32)w << 16); }

// ---- DPP row-rotate helpers (16-lane rows) ----
#define ROR1 0x121
#define ROR2 0x122
#define ROR4 0x124
#define ROR8 0x128
template<int C> __device__ __forceinline__ float dppf(float x) {
    int i = __float_as_int(x);
    return __int_as_float(__builtin_amdgcn_update_dpp(i, i, C, 0xF, 0xF, false));
}
template<int C> __device__ __forceinline__ int dppi(int x) {
    return __builtin_amdgcn_update_dpp(x, x, C, 0xF, 0xF, false);
}

// ---------------------------------------------------------------------------
// R11-proven unified GEMM (depth-2).  Measured-regression neighbors — do not
// revisit: depth-4 (R12, VGPR pressure), 64-col+bounds(256,4) (R8),
// fixup-tail w/ fences (R10), KS=32 (R14), 1024-thr k-groups (R5).
// C[64][c0..c0+128) over k-slice [k0,k0+kchunk).  grid (N/128, KS), 256 thr,
// __launch_bounds__(256,2).  W read: threads 0..15 cover one full 512B row
// segment (coalesced); W LDS k-pair-major [kp][132] u32 (2-way bank, free).
// SRC 0: A global bf16 [64][4096].  SRC 1: build X from emb (reshape quirk
//        X[r][e] = emb[2*(r&3)+(e>=128)][r>>2][e&127]).
// EPI 0: bf16 partial -> Cp16[slice].  EPI 1: bias+leaky -> bf16 Ho.
// nit = kchunk/32 must be EVEN.
// ---------------------------------------------------------------------------
template<int SRC, int EPI>
__global__ __launch_bounds__(256, 2) void k_gemm(
    const u16* __restrict__ A, const float* __restrict__ emb,
    const float* __restrict__ W, const float* __restrict__ bias,
    u16* __restrict__ Cp16, u16* __restrict__ Ho,
    int N, int kchunk)
{
    __shared__ __align__(16) u16 Alds[64][40];     // 5120 B
    __shared__ __align__(16) u32 Wlds[16 * 132];   // 8448 B
    int tid = threadIdx.x;
    int wv = tid >> 6, lane = tid & 63, c = lane & 15, g = lane >> 4;
    int c0 = blockIdx.x * 128;
    int k0 = blockIdx.y * kchunk;
    int nit = kchunk >> 5;

    int ar = tid >> 2, aseg = tid & 3;          // A staging: row, 8-elem seg
    int kp = tid >> 4, cbase = (tid & 15) * 8;  // W staging: k-pair, col base

    f32x4 acc[8];
    #pragma unroll
    for (int n = 0; n < 8; ++n) acc[n] = (f32x4){0.f, 0.f, 0.f, 0.f};

    auto loadA = [&](int kc, uint4& av) {
        if (SRC == 0) {
            av = *(const uint4*)(A + (size_t)ar * 4096 + k0 + kc + aseg * 8);
        } else {
            int e0 = kc + aseg * 8;
            int b = 2 * (ar & 3) + (e0 >> 7), d = e0 & 127;
            const float4* s = (const float4*)(emb + (b * 16 + (ar >> 2)) * 128 + d);
            float4 f0 = s[0], f1 = s[1];
            av.x = pack2(f0.x, f0.y); av.y = pack2(f0.z, f0.w);
            av.z = pack2(f1.x, f1.y); av.w = pack2(f1.z, f1.w);
        }
    };
    auto loadW = [&](int kc, float4& q0, float4& q1, float4& q2, float4& q3) {
        const float* s0 = W + (size_t)(k0 + kc + 2 * kp) * N + c0 + cbase;
        q0 = ((const float4*)s0)[0]; q1 = ((const float4*)s0)[1];
        const float* s1 = s0 + N;
        q2 = ((const float4*)s1)[0]; q3 = ((const float4*)s1)[1];
    };
    auto stage = [&](const uint4& av, const float4& q0, const float4& q1,
                     const float4& q2, const float4& q3) {
        *(uint4*)&Alds[ar][aseg * 8] = av;
        uint4 w0, w1;
        w0.x = pack2(q0.x, q2.x); w0.y = pack2(q0.y, q2.y);
        w0.z = pack2(q0.z, q2.z); w0.w = pack2(q0.w, q2.w);
        w1.x = pack2(q1.x, q3.x); w1.y = pack2(q1.y, q3.y);
        w1.z = pack2(q1.z, q3.z); w1.w = pack2(q1.w, q3.w);
        uint4* wd = (uint4*)&Wlds[kp * 132 + cbase];
        wd[0] = w0; wd[1] = w1;
    };
    auto compute = [&]() {
        short8 a8 = *(const short8*)&Alds[wv * 16 + c][g * 8];
        #pragma unroll
        for (int n = 0; n < 8; ++n) {
            int base = n * 16 + c;
            union { u32 u[4]; short8 s; } bb;
            bb.u[0] = Wlds[(g * 4 + 0) * 132 + base];
            bb.u[1] = Wlds[(g * 4 + 1) * 132 + base];
            bb.u[2] = Wlds[(g * 4 + 2) * 132 + base];
            bb.u[3] = Wlds[(g * 4 + 3) * 132 + base];
            acc[n] = __builtin_amdgcn_mfma_f32_16x16x32_bf16(a8, bb.s, acc[n], 0, 0, 0);
        }
    };

    // ---- depth-2 pipeline, two named register sets (static indexing)
    uint4 avA, avB;
    float4 qA0, qA1, qA2, qA3, qB0, qB1, qB2, qB3;
    loadA(0, avA);  loadW(0, qA0, qA1, qA2, qA3);
    loadA(32, avB); loadW(32, qB0, qB1, qB2, qB3);

    for (int it = 0; it < nit; it += 2) {
        stage(avA, qA0, qA1, qA2, qA3);
        __syncthreads();
        if (it + 2 < nit) { loadA((it + 2) * 32, avA); loadW((it + 2) * 32, qA0, qA1, qA2, qA3); }
        compute();
        __syncthreads();

        stage(avB, qB0, qB1, qB2, qB3);
        __syncthreads();
        if (it + 3 < nit) { loadA((it + 3) * 32, avB); loadW((it + 3) * 32, qB0, qB1, qB2, qB3); }
        compute();
        __syncthreads();
    }

    // ---- epilogue (D layout: col = lane&15, row = g*4+rr)
    #pragma unroll
    for (int n = 0; n < 8; ++n) {
        #pragma unroll
        for (int rr = 0; rr < 4; ++rr) {
            int grow = wv * 16 + g * 4 + rr;
            int gcol = c0 + n * 16 + c;
            float v = acc[n][rr];
            if (EPI == 0) {
                Cp16[(size_t)blockIdx.y * 64 * N + (size_t)grow * N + gcol] = f2bf(v);
            } else {
                v += bias[gcol];
                v = (v >= 0.f) ? v : 0.01f * v;
                Ho[(size_t)grow * N + gcol] = f2bf(v);
            }
        }
    }
}

// ---------------------------------------------------------------------------
// Reduce bf16 split-K partials + bias + leaky; mode 0 -> bf16 H, mode 1 ->
// sigmoid(leaky) fp32.  grid = 64*N/256 (1024 blocks at N=4096 — keep the
// parallelism; 128-block vectorized variant regressed in R13).
// ---------------------------------------------------------------------------
__global__ void k_reduce(const u16* __restrict__ Cp16, const float* __restrict__ bias,
                         u16* __restrict__ Hb, float* __restrict__ Pf,
                         int N, int ksplit, int mode)
{
    int idx = blockIdx.x * 256 + threadIdx.x;
    int col = idx & (N - 1);
    float s = bias[col];
    #pragma unroll 4
    for (int k = 0; k < ksplit; ++k) s += bf2f(Cp16[(size_t)k * 64 * N + idx]);
    float a = (s >= 0.f) ? s : 0.01f * s;
    if (mode == 0) Hb[idx] = f2bf(a);
    else           Pf[idx] = 1.0f / (1.0f + __expf(-a));
}

// ---------------------------------------------------------------------------
// 50 power iterations (VALU/DPP only) + factored output reduction.
// (L4-reduce fusion into this kernel regressed ~+10 us in R12/R13 — one
// block pulling 1 MB serially; keep the separate 64-block reduce.)
// ---------------------------------------------------------------------------
__global__ __launch_bounds__(1024) void k_power_out(
    const float* __restrict__ pol,  // [64][16][16] fp32 (post-sigmoid)
    const float* __restrict__ Ts,   // [8][16][16]
    float* __restrict__ out)        // [8][16]
{
    __shared__ float pol_lds[16384];
    __shared__ float w_lds[64][16];
    __shared__ float Ts_lds[2048];
    __shared__ float Cmat[8][16];

    int tid = threadIdx.x;
    int m = tid >> 4, r = tid & 15;

    {   // stage all 64 matrices (64 KB) to LDS
        const float4* p4 = (const float4*)(pol + tid * 16);
        float4* q4 = (float4*)&pol_lds[tid * 16];
        q4[0] = p4[0]; q4[1] = p4[1]; q4[2] = p4[2]; q4[3] = p4[3];
    }
    Ts_lds[tid] = Ts[tid];
    Ts_lds[tid + 1024] = Ts[tid + 1024];
    __syncthreads();

    // gather row r of matrix m with DPP-rotated index (matches va rotation)
    float Mr[8], Ms[8];
    {
        int mb = m * 256 + r * 16;
        int idx = r;
        #pragma unroll
        for (int k = 0; k < 8; ++k) { Mr[k] = pol_lds[mb + idx]; idx = dppi<ROR1>(idx); }
        #pragma unroll
        for (int k = 0; k < 8; ++k) { Ms[k] = pol_lds[mb + idx]; idx = dppi<ROR1>(idx); }
    }

    float v = 1.0f;
    #pragma unroll 1
    for (int it = 0; it < 50; ++it) {
        float va = v, vb = dppf<ROR8>(v);
        float w = 0.f, w2 = 0.f;
        #pragma unroll
        for (int k = 0; k < 8; ++k) {
            w  = fmaf(Mr[k], va, w);
            w2 = fmaf(Ms[k], vb, w2);
            if (k < 7) { va = dppf<ROR1>(va); vb = dppf<ROR1>(vb); }
        }
        w += w2;
        if ((it & 7) == 7) {   // positive-sum renorm; scale cancels in output
            float s = w;
            s += dppf<ROR8>(s); s += dppf<ROR4>(s);
            s += dppf<ROR2>(s); s += dppf<ROR1>(s);
            w *= 1.0f / s;
        }
        v = w;
    }
    w_lds[m][r] = v;
    __syncthreads();

    if (tid < 128) {
        int b = tid >> 4, x = tid & 15;
        float s = 0.f;
        if (b < 4) {                             // R[b][s=x] = sum_t Ts[b][x][t]
            const float* row = &Ts_lds[(b * 16 + x) * 16];
            #pragma unroll
            for (int t = 0; t < 16; ++t) s += row[t];
        } else {                                 // C[b][t=x]
            int j = b - 4;
            #pragma unroll
            for (int si = 0; si < 16; ++si)
                s += Ts_lds[(b * 16 + si) * 16 + x] / w_lds[x * 4 + j][si];
        }
        Cmat[b][x] = s;
    }
    __syncthreads();

    if (tid < 128) {
        int b = tid >> 4, n = tid & 15;
        float o = 0.f;
        if (b < 4) {
            #pragma unroll
            for (int si = 0; si < 16; ++si) {
                const float* wr = w_lds[si * 4 + b];
                o += wr[n] / wr[si] * Cmat[b][si];
            }
        } else {
            int j = b - 4;
            #pragma unroll
            for (int t = 0; t < 16; ++t)
                o += w_lds[t * 4 + j][n] * Cmat[b][t];
        }
        out[b * 16 + n] = o;
    }
}

// ---------------------------------------------------------------------------
extern "C" void kernel_launch(void* const* d_in, const int* in_sizes, int n_in,
                              void* d_out, int out_size, void* d_ws, size_t ws_size,
                              hipStream_t stream)
{
    const float* emb = (const float*)d_in[0];
    const float* Ts  = (const float*)d_in[2];
    const float* W1  = (const float*)d_in[3];  const float* b1 = (const float*)d_in[4];
    const float* W2  = (const float*)d_in[5];  const float* b2 = (const float*)d_in[6];
    const float* W3  = (const float*)d_in[7];  const float* b3 = (const float*)d_in[8];
    const float* W4  = (const float*)d_in[9];  const float* b4 = (const float*)d_in[10];
    float* outp = (float*)d_out;

    char* ws = (char*)d_ws;
    u16*   Ha  = (u16*)(ws + 0);            // 512 KB  [64][4096] bf16
    u16*   Hb  = (u16*)(ws + 524288);       // 512 KB  [64][4096] bf16
    float* pol = (float*)(ws + 1048576);    //  64 KB  [64][16][16] fp32
    u16*   Cp  = (u16*)(ws + 1114112);      //  bf16 split-K partials (KS*512 KB)

    // mid-layer ksplit: 16 (R11-proven optimum; KS=32 regressed in R14)
    size_t need16 = (size_t)1114112 + (size_t)16 * 524288;   // ~9.5 MB
    int KS = (ws_size >= need16) ? 16 : 8;
    int kchunk = 4096 / KS;   // nit = 16 or 32... -> 256/512 -> nit 8/16, even

    // L1: fused build-X + GEMM + epilogue -> Ha   (K=256, nit=8)
    k_gemm<1, 1><<<dim3(32, 1), 256, 0, stream>>>(
        nullptr, emb, W1, b1, nullptr, Ha, 4096, 256);

    // L2: split-K -> Cp (bf16); reduce -> Hb
    k_gemm<0, 0><<<dim3(32, KS), 256, 0, stream>>>(
        Ha, nullptr, W2, nullptr, Cp, nullptr, 4096, kchunk);
    k_reduce<<<1024, 256, 0, stream>>>(Cp, b2, Hb, nullptr, 4096, KS, 0);

    // L3: split-K -> Cp; reduce -> Ha
    k_gemm<0, 0><<<dim3(32, KS), 256, 0, stream>>>(
        Hb, nullptr, W3, nullptr, Cp, nullptr, 4096, kchunk);
    k_reduce<<<1024, 256, 0, stream>>>(Cp, b3, Ha, nullptr, 4096, KS, 0);

    // L4: N=256, split-K KS=32 (kchunk=128, nit=4) -> Cp; reduce+sigmoid -> pol
    k_gemm<0, 0><<<dim3(2, 32), 256, 0, stream>>>(
        Ha, nullptr, W4, nullptr, Cp, nullptr, 256, 128);
    k_reduce<<<64, 256, 0, stream>>>(Cp, b4, nullptr, pol, 256, 32, 1);

    // Power iteration + factored output
    k_power_out<<<1, 1024, 0, stream>>>(pol, Ts, outp);

    (void)in_sizes; (void)n_in; (void)out_size; (void)ws_size;
}